// Round 1
// baseline (269.291 us; speedup 1.0000x reference)
//
#include <hip/hip_runtime.h>
#include <hip/hip_bf16.h>
#include <math.h>

typedef unsigned short u16;

#define BATCH 16384
#define HID   512
#define KDIM  1024   // INPUT + HIDDEN
#define BM    128
#define BN    32     // per-gate N tile (x4 gates = 128 effective)
#define BK    64

typedef __bf16 bf16x8 __attribute__((ext_vector_type(8)));
typedef float  floatx4 __attribute__((ext_vector_type(4)));

__device__ __forceinline__ void async_copy16(const void* g, void* l) {
  __builtin_amdgcn_global_load_lds(
      (const __attribute__((address_space(1))) void*)g,
      (__attribute__((address_space(3))) void*)l, 16, 0, 0);
}

__device__ __forceinline__ float fast_sigmoid(float x) {
  return 1.0f / (1.0f + __expf(-x));
}
__device__ __forceinline__ float fast_tanh(float x) {
  float e = __expf(-2.0f * fabsf(x));
  float t = (1.0f - e) / (1.0f + e);
  return x >= 0.0f ? t : -t;
}
__device__ __forceinline__ u16 f2bf(float f) {
  return __builtin_bit_cast(u16, __float2bfloat16(f));
}

// ---------- pre-pass: fp32 -> bf16 packing into workspace ----------

// X[b][0:512] = prev_h[b], X[b][512:1024] = input_[b]. One block per row.
__global__ void pack_x_kernel(const float* __restrict__ input_,
                              const float* __restrict__ prev_h,
                              u16* __restrict__ Xb) {
  int b = blockIdx.x;
  int col = threadIdx.x * 4;
  const float* src = (col < HID) ? (prev_h + (size_t)b * HID + col)
                                 : (input_ + (size_t)b * HID + (col - HID));
  float4 v = *(const float4*)src;
  ushort4 o;
  o.x = f2bf(v.x); o.y = f2bf(v.y); o.z = f2bf(v.z); o.w = f2bf(v.w);
  *(ushort4*)(Xb + (size_t)b * KDIM + col) = o;
}

// Wb rows 0..511=W_i, 512..1023=W_f, 1024..1535=W_o, 1536..2047=W_g.
__global__ void pack_w_kernel(const float* __restrict__ Wi,
                              const float* __restrict__ Wf,
                              const float* __restrict__ Wo,
                              const float* __restrict__ Wg,
                              u16* __restrict__ Wb) {
  int grow = blockIdx.x;              // 0..2047 (uniform per block)
  int col = threadIdx.x * 4;
  int gate = grow >> 9;
  int n = grow & (HID - 1);
  const float* s = gate == 0 ? Wi : gate == 1 ? Wf : gate == 2 ? Wo : Wg;
  float4 v = *(const float4*)(s + (size_t)n * KDIM + col);
  ushort4 o;
  o.x = f2bf(v.x); o.y = f2bf(v.y); o.z = f2bf(v.z); o.w = f2bf(v.w);
  *(ushort4*)(Wb + (size_t)grow * KDIM + col) = o;
}

// ---------- main fused GEMM + LSTM epilogue ----------
// Block: 256 threads (4 waves). Tile: BM=128 batch rows x BN=32 hidden cols
// x 4 gates (effective 128x128 GEMM tile). Wave w: m_off=(w>>1)*64,
// n_off=(w&1)*16; per wave 4 m-tiles x 1 n-tile x 4 gates of 16x16x32 MFMA.
// Epilogue: all 4 gate accumulators live in the SAME lane for the same
// (batch,j) -> combine in registers, no LDS round-trip.
__global__ __launch_bounds__(256) void lstm_gemm_kernel(
    const u16* __restrict__ Xb, const u16* __restrict__ Wb,
    const float* __restrict__ Bi, const float* __restrict__ Bf,
    const float* __restrict__ Bo, const float* __restrict__ Bg,
    const float* __restrict__ prevC, float* __restrict__ out) {
  __shared__ u16 lds[16384];   // A: [0,8192) = 128x64, B: [8192,16384) = 128x64

  const int tid = threadIdx.x;
  const int wave = tid >> 6, lane = tid & 63;
  const int lrow = lane & 15, lquad = lane >> 4;
  const int m_block = blockIdx.x * BM;
  const int n_block = blockIdx.y * BN;
  const int m_off = (wave >> 1) * 64;
  const int n_off = (wave & 1) * 16;

  // Staging: 32 wave-loads of 1KiB per K-step (16 A + 16 B), 8 per wave.
  // Each wave-load covers 8 rows x 64 bf16; lane l -> row +l/8, k +(l&7)*8.
  const u16* gp[8];
  u16* lp[8];
#pragma unroll
  for (int i = 0; i < 8; ++i) {
    int li = wave * 8 + i;
    if (li < 16) {
      int row = m_block + li * 8 + (lane >> 3);
      gp[i] = Xb + (size_t)row * KDIM + (lane & 7) * 8;
      lp[i] = &lds[li * 512];                       // HW adds lane*16B
    } else {
      int br = (li - 16) * 8 + (lane >> 3);         // 0..127
      int grow = (br >> 5) * HID + n_block + (br & 31);
      gp[i] = Wb + (size_t)grow * KDIM + (lane & 7) * 8;
      lp[i] = &lds[8192 + (li - 16) * 512];
    }
  }

  floatx4 acc[4][4];   // [gate][m-tile]
#pragma unroll
  for (int g = 0; g < 4; ++g)
#pragma unroll
    for (int mt = 0; mt < 4; ++mt)
      acc[g][mt] = (floatx4){0.f, 0.f, 0.f, 0.f};

  for (int k0 = 0; k0 < KDIM; k0 += BK) {
    __syncthreads();                  // prev iter's frag reads done
#pragma unroll
    for (int i = 0; i < 8; ++i)
      async_copy16(gp[i] + k0, lp[i]);
    __syncthreads();                  // compiler drains vmcnt(0) before barrier

#pragma unroll
    for (int kk = 0; kk < 2; ++kk) {
      const int ak = kk * 32 + lquad * 8;
      bf16x8 a[4], b[4];
#pragma unroll
      for (int mt = 0; mt < 4; ++mt)
        a[mt] = *(const bf16x8*)&lds[(m_off + mt * 16 + lrow) * 64 + ak];
#pragma unroll
      for (int g = 0; g < 4; ++g)
        b[g] = *(const bf16x8*)&lds[8192 + (g * 32 + n_off + lrow) * 64 + ak];
#pragma unroll
      for (int g = 0; g < 4; ++g)
#pragma unroll
        for (int mt = 0; mt < 4; ++mt)
          acc[g][mt] = __builtin_amdgcn_mfma_f32_16x16x32_bf16(
              a[mt], b[g], acc[g][mt], 0, 0, 0);
    }
  }

  // Epilogue. C layout (verified m89): col=lane&15, row=(lane>>4)*4+reg.
  const int j = n_block + n_off + lrow;
  const float vbi = Bi[j], vbf = Bf[j], vbo = Bo[j], vbg = Bg[j];
  float* outH = out;
  float* outC = out + (size_t)BATCH * HID;
#pragma unroll
  for (int mt = 0; mt < 4; ++mt) {
    int rowb = m_block + m_off + mt * 16 + lquad * 4;
#pragma unroll
    for (int r = 0; r < 4; ++r) {
      int row = rowb + r;
      float gi = fast_sigmoid(acc[0][mt][r] + vbi);
      float gf = fast_sigmoid(acc[1][mt][r] + vbf);
      float go = fast_sigmoid(acc[2][mt][r] + vbo);
      float gg = fast_tanh(acc[3][mt][r] + vbg);
      float c = gf * prevC[row * HID + j] + gi * gg;
      float h = fast_tanh(c) * go;
      outH[row * HID + j] = h;
      outC[row * HID + j] = c;
    }
  }
}

// ---------- slow fallback if ws too small (correctness insurance) ----------
__global__ void lstm_fallback_kernel(
    const float* __restrict__ input_, const float* __restrict__ prev_h,
    const float* __restrict__ prevC,
    const float* __restrict__ Wi, const float* __restrict__ Bi,
    const float* __restrict__ Wf, const float* __restrict__ Bf,
    const float* __restrict__ Wo, const float* __restrict__ Bo,
    const float* __restrict__ Wg, const float* __restrict__ Bg,
    float* __restrict__ out) {
  int idx = blockIdx.x * blockDim.x + threadIdx.x;   // one thread per (b,j)
  int b = idx / HID, j = idx % HID;
  if (b >= BATCH) return;
  float si = 0.f, sf = 0.f, so = 0.f, sg = 0.f;
  for (int k = 0; k < KDIM; ++k) {
    float x = (k < HID) ? prev_h[b * HID + k] : input_[b * HID + (k - HID)];
    si += x * Wi[j * KDIM + k];
    sf += x * Wf[j * KDIM + k];
    so += x * Wo[j * KDIM + k];
    sg += x * Wg[j * KDIM + k];
  }
  float gi = fast_sigmoid(si + Bi[j]);
  float gf = fast_sigmoid(sf + Bf[j]);
  float go = fast_sigmoid(so + Bo[j]);
  float gg = fast_tanh(sg + Bg[j]);
  float c = gf * prevC[b * HID + j] + gi * gg;
  out[b * HID + j] = fast_tanh(c) * go;
  out[(size_t)BATCH * HID + b * HID + j] = c;
}

extern "C" void kernel_launch(void* const* d_in, const int* in_sizes, int n_in,
                              void* d_out, int out_size, void* d_ws, size_t ws_size,
                              hipStream_t stream) {
  const float* input_ = (const float*)d_in[0];
  const float* prev_h = (const float*)d_in[1];
  const float* prev_c = (const float*)d_in[2];
  const float* W_i = (const float*)d_in[3];
  const float* b_i = (const float*)d_in[4];
  const float* W_f = (const float*)d_in[5];
  const float* b_f = (const float*)d_in[6];
  const float* W_g = (const float*)d_in[7];
  const float* b_g = (const float*)d_in[8];
  const float* W_o = (const float*)d_in[9];
  const float* b_o = (const float*)d_in[10];
  float* out = (float*)d_out;

  const size_t ws_needed =
      (size_t)BATCH * KDIM * sizeof(u16) + (size_t)4 * HID * KDIM * sizeof(u16);

  if (ws_size < ws_needed) {
    int total = BATCH * HID;
    lstm_fallback_kernel<<<(total + 255) / 256, 256, 0, stream>>>(
        input_, prev_h, prev_c, W_i, b_i, W_f, b_f, W_o, b_o, W_g, b_g, out);
    return;
  }

  u16* Xb = (u16*)d_ws;                       // 16384 x 1024 bf16 = 33.5 MB
  u16* Wb = Xb + (size_t)BATCH * KDIM;        // 2048  x 1024 bf16 =  4  MB

  pack_x_kernel<<<BATCH, 256, 0, stream>>>(input_, prev_h, Xb);
  pack_w_kernel<<<4 * HID, 256, 0, stream>>>(W_i, W_f, W_o, W_g, Wb);

  dim3 grid(BATCH / BM, HID / BN);            // 128 x 16 = 2048 blocks
  lstm_gemm_kernel<<<grid, 256, 0, stream>>>(Xb, Wb, b_i, b_f, b_o, b_g,
                                             prev_c, out);
}

// Round 2
// 244.682 us; speedup vs baseline: 1.1006x; 1.1006x over previous
//
#include <hip/hip_runtime.h>
#include <hip/hip_bf16.h>
#include <math.h>

typedef unsigned short u16;

#define BATCH 16384
#define HID   512
#define KDIM  1024   // INPUT + HIDDEN
#define BM    128
#define BN    32     // per-gate N tile (x4 gates = 128 effective)
#define BK    64

typedef __bf16 bf16x8 __attribute__((ext_vector_type(8)));
typedef float  floatx4 __attribute__((ext_vector_type(4)));

__device__ __forceinline__ void async_copy16(const void* g, void* l) {
  __builtin_amdgcn_global_load_lds(
      (const __attribute__((address_space(1))) void*)g,
      (__attribute__((address_space(3))) void*)l, 16, 0, 0);
}

__device__ __forceinline__ float fast_sigmoid(float x) {
  return 1.0f / (1.0f + __expf(-x));
}
__device__ __forceinline__ float fast_tanh(float x) {
  float e = __expf(-2.0f * fabsf(x));
  float t = (1.0f - e) / (1.0f + e);
  return x >= 0.0f ? t : -t;
}
__device__ __forceinline__ u16 f2bf(float f) {
  return __builtin_bit_cast(u16, __float2bfloat16(f));
}

// ---------- pre-pass: fp32 -> bf16 packing into workspace (single kernel) ----
// Blocks [0, BATCH): X rows.  X[b][0:512]=prev_h[b], X[b][512:1024]=input_[b].
// Blocks [BATCH, BATCH+2048): W rows, order [W_i | W_f | W_o | W_g].
__global__ __launch_bounds__(256) void pack_kernel(
    const float* __restrict__ input_, const float* __restrict__ prev_h,
    const float* __restrict__ Wi, const float* __restrict__ Wf,
    const float* __restrict__ Wo, const float* __restrict__ Wg,
    u16* __restrict__ Xb, u16* __restrict__ Wb) {
  int blk = blockIdx.x;
  int col = threadIdx.x * 4;
  const float* src;
  u16* dst;
  if (blk < BATCH) {
    src = (col < HID) ? (prev_h + (size_t)blk * HID + col)
                      : (input_ + (size_t)blk * HID + (col - HID));
    dst = Xb + (size_t)blk * KDIM + col;
  } else {
    int grow = blk - BATCH;               // 0..2047
    int gate = grow >> 9;
    int n = grow & (HID - 1);
    const float* s = gate == 0 ? Wi : gate == 1 ? Wf : gate == 2 ? Wo : Wg;
    src = s + (size_t)n * KDIM + col;
    dst = Wb + (size_t)grow * KDIM + col;
  }
  float4 v = *(const float4*)src;
  ushort4 o;
  o.x = f2bf(v.x); o.y = f2bf(v.y); o.z = f2bf(v.z); o.w = f2bf(v.w);
  *(ushort4*)dst = o;
}

// ---------- main fused GEMM + LSTM epilogue ----------
// Block: 256 threads (4 waves). Tile: BM=128 batch rows x BN=32 hidden cols
// x 4 gates (effective 128x128). Wave w: m_off=(w>>1)*64, n_off=(w&1)*16.
//
// LDS layout is XOR-swizzled to kill ds_read_b128 bank conflicts:
// LDS tiles are [row][chunk] with chunk = 16B (8 bf16); slot (row,p) holds
// global chunk p ^ (row&7). global_load_lds forces dest = base + lane*16B,
// so the swizzle is applied on the GLOBAL pointer side: lane l fetches
// global chunk (l&7)^(l>>3) of row l>>3 within its 8-row group. Fragment
// reads address chunk c^(lrow&7): per lquad, 16 lanes cover all 8 chunk
// positions twice -> 2-way bank aliasing = free (m136). R1: conflicts were
// 2.5e7 (12 extra cyc/read) with the naive stride-64 layout.
__global__ __launch_bounds__(256) void lstm_gemm_kernel(
    const u16* __restrict__ Xb, const u16* __restrict__ Wb,
    const float* __restrict__ Bi, const float* __restrict__ Bf,
    const float* __restrict__ Bo, const float* __restrict__ Bg,
    const float* __restrict__ prevC, float* __restrict__ out) {
  __shared__ u16 lds[16384];   // A: [0,8192) = 128x64, B: [8192,16384) = 128x64

  const int tid = threadIdx.x;
  const int wave = tid >> 6, lane = tid & 63;
  const int lrow = lane & 15, lquad = lane >> 4;
  const int m_block = blockIdx.x * BM;
  const int n_block = blockIdx.y * BN;
  const int m_off = (wave >> 1) * 64;
  const int n_off = (wave & 1) * 16;

  // Staging: 32 wave-loads of 1KiB per K-step (16 A + 16 B), 8 per wave.
  // Wave-load li covers rows li*8+(lane>>3); lane fetches swizzled chunk.
  const int swz = ((lane & 7) ^ (lane >> 3)) * 8;   // swizzled k-offset (elems)
  const u16* gp[8];
  u16* lp[8];
#pragma unroll
  for (int i = 0; i < 8; ++i) {
    int li = wave * 8 + i;
    if (li < 16) {
      int row = m_block + li * 8 + (lane >> 3);
      gp[i] = Xb + (size_t)row * KDIM + swz;
      lp[i] = &lds[li * 512];                       // HW adds lane*16B
    } else {
      int br = (li - 16) * 8 + (lane >> 3);         // 0..127
      int grow = (br >> 5) * HID + n_block + (br & 31);
      gp[i] = Wb + (size_t)grow * KDIM + swz;
      lp[i] = &lds[8192 + (li - 16) * 512];
    }
  }

  floatx4 acc[4][4];   // [gate][m-tile]
#pragma unroll
  for (int g = 0; g < 4; ++g)
#pragma unroll
    for (int mt = 0; mt < 4; ++mt)
      acc[g][mt] = (floatx4){0.f, 0.f, 0.f, 0.f};

  const int rswz = (lrow & 7);   // row part of the read-side chunk swizzle

  for (int k0 = 0; k0 < KDIM; k0 += BK) {
    __syncthreads();                  // prev iter's frag reads done
#pragma unroll
    for (int i = 0; i < 8; ++i)
      async_copy16(gp[i] + k0, lp[i]);
    __syncthreads();                  // drains vmcnt(0) before barrier

#pragma unroll
    for (int kk = 0; kk < 2; ++kk) {
      const int c = kk * 4 + lquad;           // chunk index within the row
      const int ak = (c ^ rswz) * 8;          // swizzled element offset
      bf16x8 a[4], b[4];
#pragma unroll
      for (int mt = 0; mt < 4; ++mt)
        a[mt] = *(const bf16x8*)&lds[(m_off + mt * 16 + lrow) * 64 + ak];
#pragma unroll
      for (int g = 0; g < 4; ++g)
        b[g] = *(const bf16x8*)&lds[8192 + (g * 32 + n_off + lrow) * 64 + ak];
#pragma unroll
      for (int g = 0; g < 4; ++g)
#pragma unroll
        for (int mt = 0; mt < 4; ++mt)
          acc[g][mt] = __builtin_amdgcn_mfma_f32_16x16x32_bf16(
              a[mt], b[g], acc[g][mt], 0, 0, 0);
    }
  }

  // Epilogue. C layout (verified m89): col=lane&15, row=(lane>>4)*4+reg.
  const int j = n_block + n_off + lrow;
  const float vbi = Bi[j], vbf = Bf[j], vbo = Bo[j], vbg = Bg[j];
  float* outH = out;
  float* outC = out + (size_t)BATCH * HID;
#pragma unroll
  for (int mt = 0; mt < 4; ++mt) {
    int rowb = m_block + m_off + mt * 16 + lquad * 4;
#pragma unroll
    for (int r = 0; r < 4; ++r) {
      int row = rowb + r;
      float gi = fast_sigmoid(acc[0][mt][r] + vbi);
      float gf = fast_sigmoid(acc[1][mt][r] + vbf);
      float go = fast_sigmoid(acc[2][mt][r] + vbo);
      float gg = fast_tanh(acc[3][mt][r] + vbg);
      float c = gf * prevC[row * HID + j] + gi * gg;
      float h = fast_tanh(c) * go;
      outH[row * HID + j] = h;
      outC[row * HID + j] = c;
    }
  }
}

// ---------- slow fallback if ws too small (correctness insurance) ----------
__global__ void lstm_fallback_kernel(
    const float* __restrict__ input_, const float* __restrict__ prev_h,
    const float* __restrict__ prevC,
    const float* __restrict__ Wi, const float* __restrict__ Bi,
    const float* __restrict__ Wf, const float* __restrict__ Bf,
    const float* __restrict__ Wo, const float* __restrict__ Bo,
    const float* __restrict__ Wg, const float* __restrict__ Bg,
    float* __restrict__ out) {
  int idx = blockIdx.x * blockDim.x + threadIdx.x;   // one thread per (b,j)
  int b = idx / HID, j = idx % HID;
  if (b >= BATCH) return;
  float si = 0.f, sf = 0.f, so = 0.f, sg = 0.f;
  for (int k = 0; k < KDIM; ++k) {
    float x = (k < HID) ? prev_h[b * HID + k] : input_[b * HID + (k - HID)];
    si += x * Wi[j * KDIM + k];
    sf += x * Wf[j * KDIM + k];
    so += x * Wo[j * KDIM + k];
    sg += x * Wg[j * KDIM + k];
  }
  float gi = fast_sigmoid(si + Bi[j]);
  float gf = fast_sigmoid(sf + Bf[j]);
  float go = fast_sigmoid(so + Bo[j]);
  float gg = fast_tanh(sg + Bg[j]);
  float c = gf * prevC[b * HID + j] + gi * gg;
  out[b * HID + j] = fast_tanh(c) * go;
  out[(size_t)BATCH * HID + b * HID + j] = c;
}

extern "C" void kernel_launch(void* const* d_in, const int* in_sizes, int n_in,
                              void* d_out, int out_size, void* d_ws, size_t ws_size,
                              hipStream_t stream) {
  const float* input_ = (const float*)d_in[0];
  const float* prev_h = (const float*)d_in[1];
  const float* prev_c = (const float*)d_in[2];
  const float* W_i = (const float*)d_in[3];
  const float* b_i = (const float*)d_in[4];
  const float* W_f = (const float*)d_in[5];
  const float* b_f = (const float*)d_in[6];
  const float* W_g = (const float*)d_in[7];
  const float* b_g = (const float*)d_in[8];
  const float* W_o = (const float*)d_in[9];
  const float* b_o = (const float*)d_in[10];
  float* out = (float*)d_out;

  const size_t ws_needed =
      (size_t)BATCH * KDIM * sizeof(u16) + (size_t)4 * HID * KDIM * sizeof(u16);

  if (ws_size < ws_needed) {
    int total = BATCH * HID;
    lstm_fallback_kernel<<<(total + 255) / 256, 256, 0, stream>>>(
        input_, prev_h, prev_c, W_i, b_i, W_f, b_f, W_o, b_o, W_g, b_g, out);
    return;
  }

  u16* Xb = (u16*)d_ws;                       // 16384 x 1024 bf16 = 33.5 MB
  u16* Wb = Xb + (size_t)BATCH * KDIM;        // 2048  x 1024 bf16 =  4  MB

  pack_kernel<<<BATCH + 4 * HID, 256, 0, stream>>>(input_, prev_h,
                                                   W_i, W_f, W_o, W_g, Xb, Wb);

  dim3 grid(BATCH / BM, HID / BN);            // 128 x 16 = 2048 blocks
  lstm_gemm_kernel<<<grid, 256, 0, stream>>>(Xb, Wb, b_i, b_f, b_o, b_g,
                                             prev_c, out);
}